// Round 8
// baseline (60.762 us; speedup 1.0000x reference)
//
#include <hip/hip_runtime.h>
#include <hip/hip_cooperative_groups.h>
#include <hip/hip_bf16.h>
#include <hip/hip_fp16.h>

namespace cg = cooperative_groups;

// out[b,j] = b2[j] + sum_k w2[j,k]*(h_k - tanh(h_k)), h_k = W_k·x + b1_k, x = y^3
// W = w1 with rows 0..19 replaced by saved_param.
//
// Exact decomposition: tanh(h) = 1 - 2r, r = 1/(1+exp2(c*h)), c = 2*log2(e):
//   out_j = E_j + A_j·x + g_j(y0,y1),   g_j(y) = sum_k 2*w2_jk * r_k(y)
//   E = b2 + w2·(b1-1),  A = w2·W_eff
// g tabulated on a 65x65 grid over y in [-6,6]^2, nodes packed half2(g0,g1),
// 16.9 KB LDS table, bilinear via 2 fused ds_read2_b32/row + v_pk_fma_f16.
// Err: bilinear ~0.03 + fp16 ~0.003 vs threshold 0.142.
//
// Round 8: cooperative single-kernel (kills ~10us inter-kernel overhead), but
// with (a) host-side occupancy query to clamp the coop grid (round 7 failed:
// unchecked launch error at the exact-capacity boundary -> zero output),
// (b) grid-stride main phase so a clamped grid covers all rows,
// (c) checked return code + fallback to the proven 2-kernel path.

#define NHID 50
#define NVAR 20
#define LUTN 65
#define LUTSZ (LUTN * LUTN)       // 4225
#define LUT_INVD 5.3333333f       // 64 / 12
#define LUT_CENT 32.0f            // 6 * 64/12
#define LUT_HIC  63.999f          // clamp so iu+1 <= 64
#define FILL_BLOCKS ((LUTSZ + 511) / 512)   // 9

// ---- shared device helpers -------------------------------------------------

__device__ __forceinline__ void eval_header(int tid,
    const float* __restrict__ w1, const float* __restrict__ b1,
    const float* __restrict__ w2, const float* __restrict__ b2,
    const float* __restrict__ sp, float* __restrict__ ws)
{
    // E/A header: 6-value wave reduction over units (lanes 0..63)
    float W0 = 0.f, W1 = 0.f, bk = 0.f, w20 = 0.f, w21 = 0.f;
    if (tid < NHID) {
        W0 = (tid < NVAR) ? sp[2 * tid]     : w1[2 * tid];
        W1 = (tid < NVAR) ? sp[2 * tid + 1] : w1[2 * tid + 1];
        bk  = b1[tid];
        w20 = w2[tid];
        w21 = w2[NHID + tid];
    }
    float vals[6] = {w20 * W0, w20 * W1, w21 * W0, w21 * W1,
                     w20 * (bk - 1.f), w21 * (bk - 1.f)};
#pragma unroll
    for (int i = 0; i < 6; i++)
        for (int off = 32; off; off >>= 1)
            vals[i] += __shfl_xor(vals[i], off);
    if (tid == 0) {
        ws[1] = b2[0] + vals[4];  // E0
        ws[2] = b2[1] + vals[5];  // E1
        ws[3] = vals[0];          // A00
        ws[4] = vals[1];          // A01
        ws[5] = vals[2];          // A10
        ws[6] = vals[3];          // A11
    }
}

__device__ __forceinline__ void eval_node(int idx,
    const float* cw0, const float* cw1, const float* cb,
    const float* q0, const float* q1, float* __restrict__ ws)
{
    int iy = idx / LUTN;
    int ix = idx - iy * LUTN;
    const float D = 12.0f / 64.0f;
    float ny0 = -6.0f + ix * D;
    float ny1 = -6.0f + iy * D;
    float nx0 = ny0 * ny0 * ny0, nx1 = ny1 * ny1 * ny1;
    float g0 = 0.f, g1 = 0.f;
    for (int kk = 0; kk < NHID; kk++) {
        float t = __builtin_amdgcn_exp2f(fmaf(cw0[kk], nx0, fmaf(cw1[kk], nx1, cb[kk])));
        float r = __builtin_amdgcn_rcpf(1.0f + t);  // t=inf -> r=0 exact
        g0 = fmaf(q0[kk], r, g0);
        g1 = fmaf(q1[kk], r, g1);
    }
    __half2 h = __floats2half2_rn(g0, g1);
    ((unsigned*)(ws + 8))[idx] = *(unsigned*)&h;
}

__device__ __forceinline__ float4 bilerp_row4(float4 v, const unsigned* lut,
    float E0, float E1, float A00, float A01, float A10, float A11)
{
    float o[4];
#pragma unroll
    for (int h = 0; h < 2; h++) {
        float y0 = h ? v.z : v.x;
        float y1 = h ? v.w : v.y;
        float u = fminf(fmaxf(fmaf(y0, LUT_INVD, LUT_CENT), 0.f), LUT_HIC);
        float vv = fminf(fmaxf(fmaf(y1, LUT_INVD, LUT_CENT), 0.f), LUT_HIC);
        int iu = (int)u, iv = (int)vv;
        float fu = u - (float)iu;
        float fv = vv - (float)iv;
        int id = iv * LUTN + iu;
        unsigned u00 = lut[id],        u10 = lut[id + 1];
        unsigned u01 = lut[id + LUTN], u11 = lut[id + LUTN + 1];
        __half2 n00 = *(__half2*)&u00, n10 = *(__half2*)&u10;
        __half2 n01 = *(__half2*)&u01, n11 = *(__half2*)&u11;
        __half2 fu2 = __half2half2(__float2half_rn(fu));
        __half2 fv2 = __half2half2(__float2half_rn(fv));
        __half2 a = __hfma2(fu2, __hsub2(n10, n00), n00);
        __half2 b = __hfma2(fu2, __hsub2(n11, n01), n01);
        __half2 g = __hfma2(fv2, __hsub2(b, a), a);
        float x0 = y0 * y0 * y0;
        float x1 = y1 * y1 * y1;
        o[2 * h]     = fmaf(A00, x0, fmaf(A01, x1, E0)) + __half2float(__low2half(g));
        o[2 * h + 1] = fmaf(A10, x0, fmaf(A11, x1, E1)) + __half2float(__high2half(g));
    }
    return make_float4(o[0], o[1], o[2], o[3]);
}

// ---- cooperative single kernel ----------------------------------------------

__global__ __launch_bounds__(512) void odefunc_all(
    const float* __restrict__ y,
    const float* __restrict__ w1, const float* __restrict__ b1,
    const float* __restrict__ w2, const float* __restrict__ b2,
    const float* __restrict__ sp,
    float* __restrict__ ws,
    float* __restrict__ out, int n4, int tiles)
{
    __shared__ unsigned lut[LUTSZ];                       // 16.9 KB
    __shared__ float cw0[NHID], cw1[NHID], cb[NHID], q0[NHID], q1[NHID];

    const int tid = threadIdx.x;
    const int bid = blockIdx.x;
    const int nb  = gridDim.x;

    // Phase 0: issue first-tile y prefetch (hides under fill + grid sync)
    const float4* __restrict__ y4 = (const float4*)y;
    long long base = (long long)bid * 2048 + tid;
    float4 vin[4];
#pragma unroll
    for (int j = 0; j < 4; j++) {
        long long idx = base + (long long)j * 512;
        vin[j] = (idx < n4) ? y4[idx] : make_float4(0.f, 0.f, 0.f, 0.f);
    }

    // Phase 1: blocks 0..8 fill LUT in ws (+ block 0: header)
    if (bid < FILL_BLOCKS) {
        const float c = 2.8853900817779268f;  // 2*log2(e)
        if (tid < NHID) {
            float W0 = (tid < NVAR) ? sp[2 * tid]     : w1[2 * tid];
            float W1 = (tid < NVAR) ? sp[2 * tid + 1] : w1[2 * tid + 1];
            cw0[tid] = c * W0;
            cw1[tid] = c * W1;
            cb[tid]  = c * b1[tid];
            q0[tid]  = 2.f * w2[tid];           // w2 is [2,50] row-major
            q1[tid]  = 2.f * w2[NHID + tid];
        }
        if (bid == 0 && tid < 64) eval_header(tid, w1, b1, w2, b2, sp, ws);
        __syncthreads();
        int idx = bid * 512 + tid;
        if (idx < LUTSZ) eval_node(idx, cw0, cw1, cb, q0, q1, ws);
    }

    cg::this_grid().sync();   // device-scope acquire/release included

    // Phase 2: stage LUT to LDS; grid-stride bilinear main
    const unsigned* __restrict__ glut = (const unsigned*)(ws + 8);
    for (int i = tid; i < LUTSZ; i += 512) lut[i] = glut[i];
    const float E0 = ws[1], E1 = ws[2];
    const float A00 = ws[3], A01 = ws[4], A10 = ws[5], A11 = ws[6];
    __syncthreads();

    float4* __restrict__ o4 = (float4*)out;
    for (long long tile = bid; tile < tiles; tile += nb) {
        long long tbase = tile * 2048 + tid;
        float4 tv[4];
        if (tile == bid) {
#pragma unroll
            for (int j = 0; j < 4; j++) tv[j] = vin[j];
        } else {
#pragma unroll
            for (int j = 0; j < 4; j++) {
                long long idx = tbase + (long long)j * 512;
                tv[j] = (idx < n4) ? y4[idx] : make_float4(0.f, 0.f, 0.f, 0.f);
            }
        }
#pragma unroll
        for (int j = 0; j < 4; j++) {
            long long idx = tbase + (long long)j * 512;
            if (idx < n4)
                o4[idx] = bilerp_row4(tv[j], lut, E0, E1, A00, A01, A10, A11);
        }
    }
}

// ---- fallback two-kernel path (proven, 23.1us) -------------------------------

__global__ __launch_bounds__(256) void odefunc_lut(const float* __restrict__ w1,
                                                   const float* __restrict__ b1,
                                                   const float* __restrict__ w2,
                                                   const float* __restrict__ b2,
                                                   const float* __restrict__ sp,
                                                   float* __restrict__ ws) {
    __shared__ float cw0[NHID], cw1[NHID], cb[NHID], q0[NHID], q1[NHID];
    const float c = 2.8853900817779268f;
    int k = threadIdx.x;
    if (k < NHID) {
        float W0 = (k < NVAR) ? sp[2 * k]     : w1[2 * k];
        float W1 = (k < NVAR) ? sp[2 * k + 1] : w1[2 * k + 1];
        cw0[k] = c * W0;
        cw1[k] = c * W1;
        cb[k]  = c * b1[k];
        q0[k]  = 2.f * w2[k];
        q1[k]  = 2.f * w2[NHID + k];
    }
    if (blockIdx.x == 0 && k < 64) eval_header(k, w1, b1, w2, b2, sp, ws);
    __syncthreads();
    int idx = blockIdx.x * 256 + threadIdx.x;
    if (idx < LUTSZ) eval_node(idx, cw0, cw1, cb, q0, q1, ws);
}

__global__ __launch_bounds__(512) void odefunc_main(const float* __restrict__ y,
                                                    const float* __restrict__ wsf,
                                                    float* __restrict__ out,
                                                    int n4) {
    __shared__ unsigned lut[LUTSZ];
    const float4* __restrict__ y4 = (const float4*)y;
    float4* __restrict__ o4 = (float4*)out;

    long long base = (long long)blockIdx.x * 2048 + threadIdx.x;
    float4 vin[4];
#pragma unroll
    for (int j = 0; j < 4; j++) {
        long long idx = base + (long long)j * 512;
        vin[j] = (idx < n4) ? y4[idx] : make_float4(0.f, 0.f, 0.f, 0.f);
    }

    const unsigned* __restrict__ glut = (const unsigned*)(wsf + 8);
    for (int i = threadIdx.x; i < LUTSZ; i += 512) lut[i] = glut[i];
    const float E0 = wsf[1], E1 = wsf[2];
    const float A00 = wsf[3], A01 = wsf[4], A10 = wsf[5], A11 = wsf[6];
    __syncthreads();

#pragma unroll
    for (int j = 0; j < 4; j++) {
        long long idx = base + (long long)j * 512;
        if (idx < n4)
            o4[idx] = bilerp_row4(vin[j], lut, E0, E1, A00, A01, A10, A11);
    }
}

extern "C" void kernel_launch(void* const* d_in, const int* in_sizes, int n_in,
                              void* d_out, int out_size, void* d_ws, size_t ws_size,
                              hipStream_t stream) {
    // inputs: 0=t(int,1), 1=y(B*2), 2=w1(100), 3=b1(50), 4=w2(100), 5=b2(2), 6=saved_param(40)
    const float* y  = (const float*)d_in[1];
    const float* w1 = (const float*)d_in[2];
    const float* b1 = (const float*)d_in[3];
    const float* w2 = (const float*)d_in[4];
    const float* b2 = (const float*)d_in[5];
    const float* sp = (const float*)d_in[6];
    float* ws  = (float*)d_ws;
    float* out = (float*)d_out;

    int n4 = in_sizes[1] / 4;                 // number of float4s in y
    int tiles = (n4 + 2047) / 2048;           // 512 thr x 4 float4 per tile

    // Host-only queries (no stream ops -> graph-capture safe): how many
    // blocks can actually be co-resident for a cooperative launch?
    int dev = 0;
    hipGetDevice(&dev);
    int numCU = 0;
    hipDeviceGetAttribute(&numCU, hipDeviceAttributeMultiprocessorCount, dev);
    int maxBlocksPerCU = 0;
    hipOccupancyMaxActiveBlocksPerMultiprocessor(
        &maxBlocksPerCU, (const void*)odefunc_all, 512, 0);

    bool launched = false;
    int coopBlocks = maxBlocksPerCU * numCU;
    if (coopBlocks > tiles) coopBlocks = tiles;
    if (coopBlocks >= FILL_BLOCKS) {
        void* args[] = {(void*)&y, (void*)&w1, (void*)&b1, (void*)&w2,
                        (void*)&b2, (void*)&sp, (void*)&ws, (void*)&out,
                        (void*)&n4, (void*)&tiles};
        hipError_t e = hipLaunchCooperativeKernel((const void*)odefunc_all,
                                                  dim3(coopBlocks), dim3(512),
                                                  args, 0, stream);
        launched = (e == hipSuccess);
    }

    if (!launched) {
        // proven 2-kernel fallback
        int lut_blocks = (LUTSZ + 255) / 256;     // 17
        odefunc_lut<<<lut_blocks, 256, 0, stream>>>(w1, b1, w2, b2, sp, ws);
        odefunc_main<<<tiles, 512, 0, stream>>>(y, ws, out, n4);
    }
}

// Round 10
// 18.427 us; speedup vs baseline: 3.2974x; 3.2974x over previous
//
#include <hip/hip_runtime.h>
#include <hip/hip_bf16.h>
#include <hip/hip_fp16.h>

// out[b,j] = b2[j] + sum_k w2[j,k]*(h_k - tanh(h_k)), h_k = W_k·x + b1_k, x = y^3
// W = w1 with rows 0..19 replaced by saved_param.
//
// Exact decomposition: tanh(h) = 1 - 2r, r = 1/(1+exp2(c*h)), c = 2*log2(e):
//   out_j = E_j + A_j·x + g_j(y0,y1),   g_j(y) = sum_k 2*w2_jk * r_k(y)
//   E = b2 + w2·(b1-1),  A = w2·W_eff
// g tabulated on a 65x65 grid over y in [-6,6]^2 (17-block fill kernel, exact
// exp2/rcp), nodes packed half2(g0,g1) -> 16.9 KB LDS table, bilinear via
// 2 ds_read2_b32/row + v_pk_fma_f16 lerp. Err ~0.03 vs threshold 0.142.
//
// Round 10 = round 9 with the nontemporal-store type fixed (clang requires a
// native vector type, not HIP_vector_type float4): LDS-ILP restructure (rows
// batched x4, all ds_reads issued into register arrays before any lerp),
// uint4 LUT staging, uniform full-block guard hoisting, nt stores.

#define NHID 50
#define NVAR 20
#define LUTN 65
#define LUTSZ (LUTN * LUTN)       // 4225
#define LUT_INVD 5.3333333f       // 64 / 12
#define LUT_CENT 32.0f            // 6 * 64/12
#define LUT_HIC  63.999f          // clamp so iu+1 <= 64

typedef float f4 __attribute__((ext_vector_type(4)));   // native vector for nt-store

// Fused prep + LUT fill. 17 blocks x 256 threads; every block recomputes the
// tiny param set locally (LDS); block 0 additionally writes the E/A header.
__global__ __launch_bounds__(256) void odefunc_lut(const float* __restrict__ w1,
                                                   const float* __restrict__ b1,
                                                   const float* __restrict__ w2,
                                                   const float* __restrict__ b2,
                                                   const float* __restrict__ sp,
                                                   float* __restrict__ ws) {
    __shared__ float cw0[NHID], cw1[NHID], cb[NHID], q0[NHID], q1[NHID];
    const float c = 2.8853900817779268f;  // 2*log2(e)
    int k = threadIdx.x;
    if (k < NHID) {
        float W0 = (k < NVAR) ? sp[2 * k]     : w1[2 * k];
        float W1 = (k < NVAR) ? sp[2 * k + 1] : w1[2 * k + 1];
        cw0[k] = c * W0;
        cw1[k] = c * W1;
        cb[k]  = c * b1[k];
        q0[k]  = 2.f * w2[k];           // w2 is [2,50] row-major
        q1[k]  = 2.f * w2[NHID + k];
    }
    if (blockIdx.x == 0 && k < 64) {
        // E/A header: 6-value wave reduction over units
        float W0 = 0.f, W1 = 0.f, bk = 0.f, w20 = 0.f, w21 = 0.f;
        if (k < NHID) {
            W0 = (k < NVAR) ? sp[2 * k]     : w1[2 * k];
            W1 = (k < NVAR) ? sp[2 * k + 1] : w1[2 * k + 1];
            bk  = b1[k];
            w20 = w2[k];
            w21 = w2[NHID + k];
        }
        float vals[6] = {w20 * W0, w20 * W1, w21 * W0, w21 * W1,
                         w20 * (bk - 1.f), w21 * (bk - 1.f)};
#pragma unroll
        for (int i = 0; i < 6; i++)
            for (int off = 32; off; off >>= 1)
                vals[i] += __shfl_xor(vals[i], off);
        if (k == 0) {
            ws[1] = b2[0] + vals[4];  // E0
            ws[2] = b2[1] + vals[5];  // E1
            ws[3] = vals[0];          // A00
            ws[4] = vals[1];          // A01
            ws[5] = vals[2];          // A10
            ws[6] = vals[3];          // A11
        }
    }
    __syncthreads();

    int idx = blockIdx.x * 256 + threadIdx.x;
    if (idx < LUTSZ) {
        int iy = idx / LUTN;
        int ix = idx - iy * LUTN;
        const float D = 12.0f / 64.0f;
        float y0 = -6.0f + ix * D;
        float y1 = -6.0f + iy * D;
        float x0 = y0 * y0 * y0, x1 = y1 * y1 * y1;
        float g0 = 0.f, g1 = 0.f;
        for (int kk = 0; kk < NHID; kk++) {
            float t = __builtin_amdgcn_exp2f(fmaf(cw0[kk], x0, fmaf(cw1[kk], x1, cb[kk])));
            float r = __builtin_amdgcn_rcpf(1.0f + t);  // t=inf -> r=0 exact
            g0 = fmaf(q0[kk], r, g0);
            g1 = fmaf(q1[kk], r, g1);
        }
        __half2 h = __floats2half2_rn(g0, g1);
        ((unsigned*)(ws + 8))[idx] = *(unsigned*)&h;
    }
}

__global__ __launch_bounds__(512) void odefunc_main(const float* __restrict__ y,
                                                    const float* __restrict__ wsf,
                                                    float* __restrict__ out,
                                                    int n4) {
    __shared__ __align__(16) unsigned lut[LUTSZ + 3];   // +3 pad for uint4 staging
    const float4* __restrict__ y4 = (const float4*)y;
    f4* __restrict__ o4 = (f4*)out;

    long long bbase = (long long)blockIdx.x * 2048;
    const bool full = (bbase + 2048) <= (long long)n4;   // uniform: no guards needed
    long long base = bbase + threadIdx.x;

    // issue y-loads FIRST so HBM latency hides under staging + barrier
    float4 vin[4];
    if (full) {
#pragma unroll
        for (int j = 0; j < 4; j++) vin[j] = y4[base + (long long)j * 512];
    } else {
#pragma unroll
        for (int j = 0; j < 4; j++) {
            long long idx = base + (long long)j * 512;
            vin[j] = (idx < n4) ? y4[idx] : make_float4(0.f, 0.f, 0.f, 0.f);
        }
    }

    // stage LUT with uint4 loads (1057 x 16B)
    const uint4* __restrict__ glut4 = (const uint4*)(wsf + 8);
    uint4* lut4 = (uint4*)lut;
    for (int i = threadIdx.x; i < (LUTSZ + 3) / 4; i += 512) lut4[i] = glut4[i];

    const float E0 = wsf[1], E1 = wsf[2];
    const float A00 = wsf[3], A01 = wsf[4], A10 = wsf[5], A11 = wsf[6];
    __syncthreads();

#pragma unroll
    for (int g = 0; g < 2; g++) {   // 2 groups x 4 rows (= 2 float4s each)
        float ry0[4], ry1[4], fu[4], fv[4];
        unsigned u00[4], u10[4], u01[4], u11[4];
        // pass A: addresses + batched LDS issue (8 ds_read2 back-to-back)
#pragma unroll
        for (int r = 0; r < 4; r++) {
            float4 v = vin[2 * g + (r >> 1)];
            float y0 = (r & 1) ? v.z : v.x;
            float y1 = (r & 1) ? v.w : v.y;
            ry0[r] = y0; ry1[r] = y1;
            float u  = fminf(fmaxf(fmaf(y0, LUT_INVD, LUT_CENT), 0.f), LUT_HIC);
            float vv = fminf(fmaxf(fmaf(y1, LUT_INVD, LUT_CENT), 0.f), LUT_HIC);
            int iu = (int)u, iv = (int)vv;
            fu[r] = u - (float)iu;
            fv[r] = vv - (float)iv;
            int id = iv * LUTN + iu;
            u00[r] = lut[id];          u10[r] = lut[id + 1];
            u01[r] = lut[id + LUTN];   u11[r] = lut[id + LUTN + 1];
        }
        // pass B: fp16 bilinear lerps + linear part
        float o0[4], o1[4];
#pragma unroll
        for (int r = 0; r < 4; r++) {
            __half2 n00 = *(__half2*)&u00[r], n10 = *(__half2*)&u10[r];
            __half2 n01 = *(__half2*)&u01[r], n11 = *(__half2*)&u11[r];
            __half2 fu2 = __half2half2(__float2half_rn(fu[r]));
            __half2 fv2 = __half2half2(__float2half_rn(fv[r]));
            __half2 a  = __hfma2(fu2, __hsub2(n10, n00), n00);
            __half2 b  = __hfma2(fu2, __hsub2(n11, n01), n01);
            __half2 gg = __hfma2(fv2, __hsub2(b, a), a);
            float x0 = ry0[r] * ry0[r] * ry0[r];
            float x1 = ry1[r] * ry1[r] * ry1[r];
            o0[r] = fmaf(A00, x0, fmaf(A01, x1, E0)) + __half2float(__low2half(gg));
            o1[r] = fmaf(A10, x0, fmaf(A11, x1, E1)) + __half2float(__high2half(gg));
        }
        // stores (write-only stream -> nontemporal)
#pragma unroll
        for (int p = 0; p < 2; p++) {
            long long idx = base + (long long)(2 * g + p) * 512;
            f4 ov = {o0[2 * p], o1[2 * p], o0[2 * p + 1], o1[2 * p + 1]};
            if (full || idx < n4)
                __builtin_nontemporal_store(ov, &o4[idx]);
        }
    }
}

extern "C" void kernel_launch(void* const* d_in, const int* in_sizes, int n_in,
                              void* d_out, int out_size, void* d_ws, size_t ws_size,
                              hipStream_t stream) {
    // inputs: 0=t(int,1), 1=y(B*2), 2=w1(100), 3=b1(50), 4=w2(100), 5=b2(2), 6=saved_param(40)
    const float* y  = (const float*)d_in[1];
    const float* w1 = (const float*)d_in[2];
    const float* b1 = (const float*)d_in[3];
    const float* w2 = (const float*)d_in[4];
    const float* b2 = (const float*)d_in[5];
    const float* sp = (const float*)d_in[6];
    float* ws  = (float*)d_ws;
    float* out = (float*)d_out;

    int lut_blocks = (LUTSZ + 255) / 256;     // 17
    odefunc_lut<<<lut_blocks, 256, 0, stream>>>(w1, b1, w2, b2, sp, ws);

    int n4 = in_sizes[1] / 4;                 // number of float4s in y
    int blocks = (n4 + 2047) / 2048;          // 512 thr x 4 float4 each = 1024
    odefunc_main<<<blocks, 512, 0, stream>>>(y, ws, out, n4);
}